// Round 12
// baseline (256.162 us; speedup 1.0000x reference)
//
#include <hip/hip_runtime.h>
#include <hip/hip_bf16.h>
#include <hip/hip_fp16.h>
#include <math.h>

#define ND 128      // feature dim D
#define NH 4        // heads
#define HD 512      // H*D

typedef __attribute__((ext_vector_type(8))) short bf16x8;
typedef __attribute__((ext_vector_type(4))) float f32x4;

__device__ __forceinline__ unsigned pack_bf16(float a, float b) {
    unsigned ua = __float_as_uint(a), ub = __float_as_uint(b);
    ua = (ua + 0x7fffu + ((ua >> 16) & 1u)) >> 16;
    ub = (ub + 0x7fffu + ((ub >> 16) & 1u)) >> 16;
    return ua | (ub << 16);
}
__device__ __forceinline__ unsigned short bf16r(float a) {
    unsigned ua = __float_as_uint(a);
    return (unsigned short)((ua + 0x7fffu + ((ua >> 16) & 1u)) >> 16);
}
__device__ __forceinline__ float bflo(unsigned u) { return __uint_as_float(u << 16); }
__device__ __forceinline__ float bfhi(unsigned u) { return __uint_as_float(u & 0xffff0000u); }
__device__ __forceinline__ unsigned pack_half2(float a, float b) {
    __half ha = __float2half(a), hb = __float2half(b);
    return (unsigned)__half_as_ushort(ha) | ((unsigned)__half_as_ushort(hb) << 16);
}
__device__ __forceinline__ float2 h22f(unsigned u) {
    __half2 h = *(__half2*)&u;
    return __half22float2(h);
}

// ---------------------------------------------------------------------------
// K0: blocks [0,256): Ws[j][K] = W[k][h*128+j] bf16 (B-operand [out][K=512]).
//     block 256: pt = W-projected att vectors. blocks 257+: dst histogram.
// ---------------------------------------------------------------------------
__global__ __launch_bounds__(256) void prep_misc(const float* __restrict__ W,
                                                 const float* __restrict__ att_src,
                                                 const float* __restrict__ att_dst,
                                                 unsigned short* __restrict__ Ws,
                                                 float* __restrict__ pt,
                                                 const int* __restrict__ dst,
                                                 int* __restrict__ cnt, int ne) {
    int b = blockIdx.x;
    if (b < 256) {
        int idx = b * 256 + threadIdx.x;        // over 128*512
        int j = idx >> 9, K = idx & 511;
        int h = K >> 7, k = K & 127;
        Ws[idx] = bf16r(W[(size_t)k * HD + h * ND + j]);
    } else if (b == 256) {
        int k = threadIdx.x;
        if (k < ND) {
            for (int h = 0; h < NH; ++h) {
                float ps = 0.f, pd = 0.f;
                for (int d = 0; d < ND; ++d) {
                    float wv = W[(size_t)k * HD + h * ND + d];
                    ps = fmaf(wv, att_src[h * ND + d], ps);
                    pd = fmaf(wv, att_dst[h * ND + d], pd);
                }
                pt[h * ND + k] = ps;
                pt[(4 + h) * ND + k] = pd;
            }
        }
    } else {
        int e = (b - 257) * 256 + threadIdx.x;
        if (e < ne) atomicAdd(&cnt[dst[e]], 1);
    }
}

// ---------------------------------------------------------------------------
// K1 fused: blocks [0, nbA): k_a_xb (one wave per node: bf16 x copy + 8
// attention logits). blocks [nbA, nbA+nbS): scanA over cnt.
// ---------------------------------------------------------------------------
__global__ __launch_bounds__(256) void ka_scanA(const float* __restrict__ x,
                                                const float* __restrict__ pt,
                                                unsigned* __restrict__ xb,
                                                float* __restrict__ a_src,
                                                float* __restrict__ a_dst,
                                                const int* __restrict__ cnt,
                                                int* __restrict__ partial,
                                                int* __restrict__ bsum,
                                                int n, int nbA) {
    __shared__ float pl[8 * ND];
    __shared__ int sh[256];
    if ((int)blockIdx.x < nbA) {
        { int t = threadIdx.x; ((float4*)pl)[t] = ((const float4*)pt)[t]; }
        __syncthreads();
        int wave = (blockIdx.x * 256 + threadIdx.x) >> 6;
        int lane = threadIdx.x & 63;
        if (wave >= n) return;
        float2 xv = ((const float2*)(x + (size_t)wave * ND))[lane];
        xb[(size_t)wave * 64 + lane] = pack_bf16(xv.x, xv.y);
#pragma unroll
        for (int o = 0; o < 8; ++o) {
            float2 pv = ((const float2*)(pl + o * ND))[lane];
            float v = xv.x * pv.x + xv.y * pv.y;
#pragma unroll
            for (int off = 1; off < 64; off <<= 1) v += __shfl_xor(v, off);
            if (lane == 0) {
                if (o < 4) a_src[(size_t)wave * NH + o] = v;
                else       a_dst[(size_t)wave * NH + (o - 4)] = v;
            }
        }
    } else {
        int bid = blockIdx.x - nbA;
        int gid = bid * 256 + threadIdx.x;
        int v = (gid < n) ? cnt[gid] : 0;
        int val = v;
        sh[threadIdx.x] = val;
        __syncthreads();
#pragma unroll
        for (int off = 1; off < 256; off <<= 1) {
            int add = (threadIdx.x >= off) ? sh[threadIdx.x - off] : 0;
            __syncthreads();
            val += add;
            sh[threadIdx.x] = val;
            __syncthreads();
        }
        if (gid < n) partial[gid] = val - v;
        if (threadIdx.x == 255) bsum[bid] = val;
    }
}

// ---------------------------------------------------------------------------
// scanBC: redundant block-sum scan + apply offset.
// ---------------------------------------------------------------------------
__global__ __launch_bounds__(256) void scanBC(const int* __restrict__ partial,
                                              const int* __restrict__ bsum,
                                              int* __restrict__ starts,
                                              int* __restrict__ cursor,
                                              int n, int ne, int nb) {
    __shared__ int sh[256];
    int t = threadIdx.x;
    int v = (t < nb) ? bsum[t] : 0;
    int val = v;
    sh[t] = val;
    __syncthreads();
#pragma unroll
    for (int off = 1; off < 256; off <<= 1) {
        int add = (t >= off) ? sh[t - off] : 0;
        __syncthreads();
        val += add;
        sh[t] = val;
        __syncthreads();
    }
    int myoff = (blockIdx.x == 0) ? 0 : sh[blockIdx.x - 1];
    int gid = blockIdx.x * 256 + t;
    if (gid < n) {
        int s = partial[gid] + myoff;
        starts[gid] = s;
        cursor[gid] = s;
    }
    if (gid == 0) starts[n] = ne;
}

// ---------------------------------------------------------------------------
// K_scatter: dst-segment permute + fp16 head weights: {src, w01, w23, pad}.
// ---------------------------------------------------------------------------
__global__ __launch_bounds__(256) void scatter_edges_w(const int* __restrict__ src,
                                                       const int* __restrict__ dst,
                                                       const float* __restrict__ a_src,
                                                       const float* __restrict__ a_dst,
                                                       int* __restrict__ cursor,
                                                       uint4* __restrict__ eperm, int ne) {
    int e = blockIdx.x * 256 + threadIdx.x;
    if (e < ne) {
        int s = src[e], t = dst[e];
        float4 as = *(const float4*)(a_src + (size_t)s * NH);
        float4 ad = *(const float4*)(a_dst + (size_t)t * NH);
        float A0 = as.x + ad.x, A1 = as.y + ad.y, A2 = as.z + ad.z, A3 = as.w + ad.w;
        A0 = (A0 > 0.f) ? A0 : 0.2f * A0;
        A1 = (A1 > 0.f) ? A1 : 0.2f * A1;
        A2 = (A2 > 0.f) ? A2 : 0.2f * A2;
        A3 = (A3 > 0.f) ? A3 : 0.2f * A3;
        float e0 = expf(A0), e1 = expf(A1), e2 = expf(A2), e3 = expf(A3);
        int pos = atomicAdd(&cursor[t], 1);
        uint4 ev;
        ev.x = (unsigned)s;
        ev.y = pack_half2(e0, e1);
        ev.z = pack_half2(e2, e3);
        ev.w = 0u;
        eperm[pos] = ev;
    }
}

// ---------------------------------------------------------------------------
// K_agg FUSED: 16 nodes per block, 4 waves x 4 nodes.
// Phase 1 (per wave, R10-proven loop): gather bf16 x rows, per-head weighted
//   sums -> u row (bf16) into swizzled LDS [16 rows][512 K].
// Phase 2: block MFMA [16x512] @ Ws^T (B-frags direct from L2-resident Ws).
// Phase 3: C (fp32, overlays u in LDS) -> per-row bias+LN+GELU+residual.
// ---------------------------------------------------------------------------
#define FMA16()                                                            \
    { float f0 = bflo(xv.x), f1 = bfhi(xv.x), f2 = bflo(xv.y), f3 = bfhi(xv.y); \
      acc[0] = fmaf(w01.x, f0, acc[0]);  acc[1] = fmaf(w01.x, f1, acc[1]);  \
      acc[2] = fmaf(w01.x, f2, acc[2]);  acc[3] = fmaf(w01.x, f3, acc[3]);  \
      acc[4] = fmaf(w01.y, f0, acc[4]);  acc[5] = fmaf(w01.y, f1, acc[5]);  \
      acc[6] = fmaf(w01.y, f2, acc[6]);  acc[7] = fmaf(w01.y, f3, acc[7]);  \
      acc[8] = fmaf(w23.x, f0, acc[8]);  acc[9] = fmaf(w23.x, f1, acc[9]);  \
      acc[10] = fmaf(w23.x, f2, acc[10]); acc[11] = fmaf(w23.x, f3, acc[11]); \
      acc[12] = fmaf(w23.y, f0, acc[12]); acc[13] = fmaf(w23.y, f1, acc[13]); \
      acc[14] = fmaf(w23.y, f2, acc[14]); acc[15] = fmaf(w23.y, f3, acc[15]); }

__global__ __launch_bounds__(256) void node_agg_fused(
        const uint4* __restrict__ eperm, const int* __restrict__ starts,
        const uint2* __restrict__ xb2, const unsigned short* __restrict__ Ws,
        const float* __restrict__ x, const float* __restrict__ bias,
        const float* __restrict__ gamma, const float* __restrict__ beta,
        float* __restrict__ out, int n) {
    __shared__ char lds[16384];   // u rows (bf16, swizzled); phase 3 overlays C fp32 [16][128]

    const int w = threadIdx.x >> 6;
    const int lane = threadIdx.x & 63;
    const int slot = lane & 31;   // dim quad
    const int half = lane >> 5;   // even/odd edge
    const int node0 = blockIdx.x * 16;

    // ---------------- phase 1: 4 nodes per wave ----------------
    for (int i = 0; i < 4; ++i) {
        const int nl = w * 4 + i;
        const int node = node0 + nl;
        int s0 = 0, s1 = 0;
        if (node < n) { s0 = starts[node]; s1 = starts[node + 1]; }

        float den0 = 0.f, den1 = 0.f, den2 = 0.f, den3 = 0.f;
        float acc[16];
#pragma unroll
        for (int j = 0; j < 16; ++j) acc[j] = 0.f;

        for (int base = s0; base < s1; base += 16) {
            int rem = s1 - base; if (rem > 16) rem = 16;
            uint4 ev = {0u, 0u, 0u, 0u};
            if (lane < rem) ev = eperm[base + lane];
            {
                float2 dl = h22f(ev.y), dh = h22f(ev.z);
                den0 += dl.x; den1 += dl.y; den2 += dh.x; den3 += dh.y;
            }
            if (rem == 16) {
#pragma unroll
                for (int pp = 0; pp < 8; ++pp) {
                    int j2 = 2 * pp + half;
                    int s = __shfl((int)ev.x, j2);
                    unsigned uy = __shfl(ev.y, j2);
                    unsigned uz = __shfl(ev.z, j2);
                    uint2 xv = xb2[(size_t)s * 32 + slot];
                    float2 w01 = h22f(uy), w23 = h22f(uz);
                    FMA16();
                }
            } else {
                for (int jj = 0; jj < rem; jj += 2) {
                    int j2 = jj + half;
                    bool valid = (j2 < rem);
                    int j2c = valid ? j2 : jj;
                    int s = __shfl((int)ev.x, j2c);
                    unsigned uy = __shfl(ev.y, j2c);
                    unsigned uz = __shfl(ev.z, j2c);
                    uint2 xv = xb2[(size_t)s * 32 + slot];
                    float2 w01 = h22f(uy), w23 = h22f(uz);
                    float m = valid ? 1.f : 0.f;
                    w01.x *= m; w01.y *= m; w23.x *= m; w23.y *= m;
                    FMA16();
                }
            }
        }

#pragma unroll
        for (int off = 1; off < 64; off <<= 1) {
            den0 += __shfl_xor(den0, off);
            den1 += __shfl_xor(den1, off);
            den2 += __shfl_xor(den2, off);
            den3 += __shfl_xor(den3, off);
        }
        float i0 = (den0 > 0.f) ? 0.25f / den0 : 0.f;
        float i1 = (den1 > 0.f) ? 0.25f / den1 : 0.f;
        float i2 = (den2 > 0.f) ? 0.25f / den2 : 0.f;
        float i3 = (den3 > 0.f) ? 0.25f / den3 : 0.f;

        float v[16];
#pragma unroll
        for (int f = 0; f < 4; ++f) {
            v[0 + f]  = acc[0 + f]  * i0;
            v[4 + f]  = acc[4 + f]  * i1;
            v[8 + f]  = acc[8 + f]  * i2;
            v[12 + f] = acc[12 + f] * i3;
        }
#pragma unroll
        for (int j = 0; j < 16; ++j) v[j] += __shfl_xor(v[j], 32);

        // write u row nl (bf16) to swizzled LDS: byte = nl*1024 + ((K*2 &~15) ^ swz) + (K*2 & 8)
#pragma unroll
        for (int hh = 0; hh < 2; ++hh) {
            int h = half * 2 + hh;
            int Kb = (h * ND + slot * 4) * 2;          // byte offset within row (8-aligned)
            int boff = nl * 1024 + ((Kb & ~15) ^ ((nl & 7) << 4)) + (Kb & 8);
            uint2 val;
            val.x = pack_bf16(v[h * 4 + 0], v[h * 4 + 1]);
            val.y = pack_bf16(v[h * 4 + 2], v[h * 4 + 3]);
            *(uint2*)(lds + boff) = val;
        }
    }
    __syncthreads();

    // ---------------- phase 2: [16 x 512] @ Ws^T via MFMA ----------------
    const int g16 = lane >> 4;    // 0..3
    const int e16 = lane & 15;    // 0..15
    f32x4 cacc[2];
    cacc[0] = (f32x4){0.f, 0.f, 0.f, 0.f};
    cacc[1] = (f32x4){0.f, 0.f, 0.f, 0.f};
#pragma unroll
    for (int t = 0; t < 16; ++t) {
        int K0 = t * 32 + 8 * g16;
        bf16x8 a = *(const bf16x8*)(lds + e16 * 1024 + ((K0 * 2) ^ ((e16 & 7) << 4)));
#pragma unroll
        for (int c2 = 0; c2 < 2; ++c2) {
            int c = w * 2 + c2;
            bf16x8 b = *(const bf16x8*)(Ws + (size_t)(c * 16 + e16) * HD + K0);
            cacc[c2] = __builtin_amdgcn_mfma_f32_16x16x32_bf16(a, b, cacc[c2], 0, 0, 0);
        }
    }
    __syncthreads();   // u reads done -> overlay C

    float* C = (float*)lds;       // [16 rows][128 cols]
#pragma unroll
    for (int c2 = 0; c2 < 2; ++c2)
#pragma unroll
        for (int ri = 0; ri < 4; ++ri)
            C[(g16 * 4 + ri) * 128 + (w * 2 + c2) * 16 + e16] = cacc[c2][ri];
    __syncthreads();

    // ---------------- phase 3: per-row bias+LN+GELU+residual ----------------
    float2 bv = ((const float2*)bias)[lane];
    float2 gv = ((const float2*)gamma)[lane];
    float2 tb = ((const float2*)beta)[lane];
    for (int i = 0; i < 4; ++i) {
        int row = w * 4 + i;
        int grow = node0 + row;
        if (grow >= n) break;
        float2 c2v = ((float2*)(C + row * 128))[lane];
        c2v.x += bv.x; c2v.y += bv.y;
        float s = c2v.x + c2v.y, s2 = c2v.x * c2v.x + c2v.y * c2v.y;
#pragma unroll
        for (int off = 1; off < 64; off <<= 1) {
            s += __shfl_xor(s, off);
            s2 += __shfl_xor(s2, off);
        }
        float mu = s * (1.0f / ND);
        float var = s2 * (1.0f / ND) - mu * mu;
        var = fmaxf(var, 0.0f);
        float inv = rsqrtf(var + 1e-5f);
        float2 xres = ((const float2*)(x + (size_t)grow * ND))[lane];
        float y0 = (c2v.x - mu) * inv * gv.x + tb.x;
        float y1 = (c2v.y - mu) * inv * gv.y + tb.y;
        y0 = 0.5f * y0 * (1.0f + erff(y0 * 0.70710678118654752f)) + xres.x;
        y1 = 0.5f * y1 * (1.0f + erff(y1 * 0.70710678118654752f)) + xres.y;
        float2 ov = {y0, y1};
        ((float2*)(out + (size_t)grow * ND))[lane] = ov;
    }
}

// ---------------------------------------------------------------------------
extern "C" void kernel_launch(void* const* d_in, const int* in_sizes, int n_in,
                              void* d_out, int out_size, void* d_ws, size_t ws_size,
                              hipStream_t stream) {
    const float* x       = (const float*)d_in[0];
    const int*   edge    = (const int*)d_in[1];   // [2, E]: src row then dst row
    const float* W       = (const float*)d_in[2];
    const float* att_src = (const float*)d_in[3];
    const float* att_dst = (const float*)d_in[4];
    const float* bias    = (const float*)d_in[5];
    const float* gamma   = (const float*)d_in[6];
    const float* beta    = (const float*)d_in[7];
    float* out = (float*)d_out;

    const int n  = in_sizes[0] / ND;   // 50000
    const int ne = in_sizes[1] / 2;    // 800000
    const int* src = edge;
    const int* dst = edge + ne;

    const int nb  = (n + 255) / 256;   // 196 (<256)
    const int nbA = (n + 3) / 4;       // k_a_xb blocks (12500)

    char* wsp = (char*)d_ws;
    unsigned* xb        = (unsigned*)wsp;        wsp += (size_t)n * 64 * sizeof(unsigned);   // bf16 x copy
    unsigned short* Ws  = (unsigned short*)wsp;  wsp += (size_t)ND * HD * sizeof(short);     // [j][K] bf16
    float* pt      = (float*)wsp;               wsp += (size_t)8 * ND * sizeof(float);
    float* a_src   = (float*)wsp;               wsp += (size_t)n * NH * sizeof(float);
    float* a_dst   = (float*)wsp;               wsp += (size_t)n * NH * sizeof(float);
    uint4* eperm   = (uint4*)wsp;               wsp += (size_t)ne * sizeof(uint4);
    int*   cnt     = (int*)wsp;                 wsp += (size_t)n * sizeof(int);
    int*   partial = (int*)wsp;                 wsp += (size_t)n * sizeof(int);
    int*   bsum    = (int*)wsp;                 wsp += 256 * sizeof(int);
    int*   starts  = (int*)wsp;                 wsp += (size_t)(n + 1) * sizeof(int);
    int*   cursor  = (int*)wsp;                 wsp += (size_t)n * sizeof(int);

    (void)hipMemsetAsync(cnt, 0, (size_t)n * sizeof(int), stream);

    prep_misc<<<257 + (ne + 255) / 256, 256, 0, stream>>>(W, att_src, att_dst,
                                                          Ws, pt, dst, cnt, ne);

    ka_scanA<<<nbA + nb, 256, 0, stream>>>(x, pt, xb, a_src, a_dst,
                                           cnt, partial, bsum, n, nbA);

    scanBC<<<nb, 256, 0, stream>>>(partial, bsum, starts, cursor, n, ne, nb);

    scatter_edges_w<<<(ne + 255) / 256, 256, 0, stream>>>(src, dst, a_src, a_dst,
                                                          cursor, eperm, ne);

    node_agg_fused<<<(n + 15) / 16, 256, 0, stream>>>(eperm, starts, (const uint2*)xb,
                                                      Ws, x, bias, gamma, beta, out, n);
}